// Round 14
// baseline (69.553 us; speedup 1.0000x reference)
//
#include <hip/hip_runtime.h>
#include <math.h>

// FactorMuE: profile-HMM forward log-likelihood.
// Dims (static): M=128, Mp1=129, K=258, D=21, ZD=64, B=64, L=256, P=774.
// Reference-fidelity detail: row k=128 of the transition matrix is all
// NEG=-1e32; the reference's float32 row-lse absorbs log(258), so the
// normalized row is 0.0 -> linear outflow weight 1.0 PER DESTINATION.
#define MP1 129
#define KK  258
#define DD  21
#define ZDIM 64
#define BB  64
#define LL  256

// ---------------- ws layout (floats) ----------------
// ETg: [64][22][64][4] transposed emission table = 360448
// E2g: [64][22][2]                               = 2816
// tok: [64][256] int32                           = 16384
#define OFF_ETG  0
#define OFF_E2G  360448
#define OFF_TOK  363264
#define OFF_COEF 379648
#define C_UU   0
#define C_DXM  258
#define C_DXI  516
#define C_WM   774
#define C_WI   903
#define C_DMID 1032
#define C_PI0  1160

#define EMIS_BLKS 65     // 260 waves >= 258 (c,m)-rows, one wave per row
#define TOK_BLKS  1366   // 5464 waves, 3 rows each, single iteration

typedef float f32x2 __attribute__((ext_vector_type(2)));

// -------- DPP helpers (cross-lane on the VALU pipe) --------
template <int CTRL, int RM, int BM>
__device__ __forceinline__ float updpp(float old, float src) {
    return __int_as_float(__builtin_amdgcn_update_dpp(
        __float_as_int(old), __float_as_int(src), CTRL, RM, BM, false));
}
__device__ __forceinline__ float readlane_f(float v, int lane) {
    return __int_as_float(__builtin_amdgcn_readlane(__float_as_int(v), lane));
}
__device__ __forceinline__ float wave_sum_to63(float s) {
    s += updpp<0x111, 0xf, 0xf>(0.f, s);   // row_shr:1
    s += updpp<0x112, 0xf, 0xf>(0.f, s);   // row_shr:2
    s += updpp<0x114, 0xf, 0xf>(0.f, s);   // row_shr:4
    s += updpp<0x118, 0xf, 0xf>(0.f, s);   // row_shr:8
    s += updpp<0x142, 0xa, 0xf>(0.f, s);   // row_bcast:15
    s += updpp<0x143, 0xc, 0xf>(0.f, s);   // row_bcast:31
    return s;
}

// ==================== fused setup: coef | emis | tok by block role ====================
__global__ __launch_bounds__(256, 1) void k_setup(const float* __restrict__ z,
                                                  const float* __restrict__ W,
                                                  const float* __restrict__ bias,
                                                  const float* __restrict__ invt,
                                                  const float* __restrict__ data,
                                                  const float* __restrict__ ins,
                                                  const float* __restrict__ del,
                                                  float* __restrict__ ETg,
                                                  float* __restrict__ E2g,
                                                  int* __restrict__ tokout,
                                                  float* __restrict__ coef) {
    __shared__ float il[774], dl[774], Smid[129], Qs[130];
    int bid = blockIdx.x;
    int tid = threadIdx.x;

    if (bid >= 1 && bid <= EMIS_BLKS) {
        // ---- emission: wave = one (c,m)-row rr, lane = batch b ----
        int b  = tid & 63;
        int rr = __builtin_amdgcn_readfirstlane((bid - 1) * 4 + (tid >> 6));
        if (rr >= KK) return;
        float it = log1pf(expf(invt[0]));          // softplus
        const float* wb = W + (size_t)rr * DD * ZDIM;   // wave-uniform
        const float* bp = bias + rr * DD;
        float acc[DD];
        #pragma unroll
        for (int d = 0; d < DD; ++d) acc[d] = bp[d];
        const float4* zp = (const float4*)(z + (size_t)b * ZDIM);
        #pragma unroll
        for (int c = 0; c < 4; ++c) {              // 4 chunks x 16 floats (no spill)
            float4 za = zp[4 * c + 0], zb = zp[4 * c + 1];
            float4 zc = zp[4 * c + 2], zd = zp[4 * c + 3];
            #pragma unroll
            for (int d = 0; d < DD; ++d) {
                const float4* wp = (const float4*)(wb + (size_t)d * ZDIM + 16 * c);
                float4 wa = wp[0], wv = wp[1], wc = wp[2], wd = wp[3];
                float a = acc[d];
                a = fmaf(za.x, wa.x, a); a = fmaf(za.y, wa.y, a);
                a = fmaf(za.z, wa.z, a); a = fmaf(za.w, wa.w, a);
                a = fmaf(zb.x, wv.x, a); a = fmaf(zb.y, wv.y, a);
                a = fmaf(zb.z, wv.z, a); a = fmaf(zb.w, wv.w, a);
                a = fmaf(zc.x, wc.x, a); a = fmaf(zc.y, wc.y, a);
                a = fmaf(zc.z, wc.z, a); a = fmaf(zc.w, wc.w, a);
                a = fmaf(zd.x, wd.x, a); a = fmaf(zd.y, wd.y, a);
                a = fmaf(zd.z, wd.z, a); a = fmaf(zd.w, wd.w, a);
                acc[d] = a;
            }
        }
        float mx = acc[0] * it;
        #pragma unroll
        for (int d = 0; d < DD; ++d) { acc[d] *= it; mx = fmaxf(mx, acc[d]); }
        float s = 0.f;
        #pragma unroll
        for (int d = 0; d < DD; ++d) { acc[d] = expf(acc[d] - mx); s += acc[d]; }
        float inv = 1.0f / s;
        // TRANSPOSED write consumed by k_fwd without repack:
        //   match m<128 : ETg[b][d][m>>1][m&1]
        //   insert m<128: ETg[b][d][m>>1][2+(m&1)]
        //   match 128 / insert 128 -> E2g[b][d][0/1]
        if (rr == 128 || rr == 257) {
            float* eb = E2g + b * 44 + ((rr == 128) ? 0 : 1);
            #pragma unroll
            for (int d = 0; d < DD; ++d) eb[d * 2] = acc[d] * inv;
            eb[DD * 2] = 1.0f;                     // ones row (missing token)
        } else {
            bool ism = rr < 128;
            int m = ism ? rr : rr - MP1;
            int slot = (m >> 1) * 4 + (ism ? 0 : 2) + (m & 1);
            float* eb = ETg + (size_t)b * 5632 + slot;
            #pragma unroll
            for (int d = 0; d < DD; ++d) eb[d * 256] = acc[d] * inv;
            eb[DD * 256] = 1.0f;                   // ones row (missing token)
        }
        return;
    }
    if (bid > EMIS_BLKS) {
        // ---- token extraction via ballot: 3 rows per wave, one iteration ----
        int wid  = (bid - 1 - EMIS_BLKS) * 4 + (tid >> 6);
        int lane = tid & 63;
        int r3   = lane / 21;                            // 0..3 (lane 63 idle)
        int d    = lane - r3 * 21;
        int row  = wid * 3 + r3;
        float v = 0.f;
        if (r3 < 3 && row < BB * LL) v = data[(size_t)row * DD + d];
        unsigned long long m = __ballot(v > 0.5f);
        if (r3 < 3 && d == 0 && row < BB * LL) {
            unsigned long long slice = (m >> (21 * r3)) & 0x1FFFFFULL;
            tokout[row] = slice ? (int)__builtin_ctzll(slice) : DD;
        }
        return;
    }
    // ---- bid 0: transition coefficients (O(1) per row via suffix-LSE) ----
    int t = tid;
    for (int p = t; p < 387; p += 256) {
        float x0 = ins[2 * p], x1 = ins[2 * p + 1];
        float mx = fmaxf(x0, x1);
        float ls = mx + logf(expf(x0 - mx) + expf(x1 - mx));
        il[2 * p] = x0 - ls; il[2 * p + 1] = x1 - ls;
        float y0 = del[2 * p], y1 = del[2 * p + 1];
        float my = fmaxf(y0, y1);
        float lt = my + logf(expf(y0 - my) + expf(y1 - my));
        dl[2 * p] = y0 - lt; dl[2 * p + 1] = y1 - lt;
    }
    __syncthreads();
    if (t < 64) {   // Smid prefix sum, wave 0
        int mmA = 1 + 2 * t, mmB = 2 + 2 * t;
        float xA = il[(mmA * 3 + 2) * 2 + 0] + dl[(mmA * 3 + 2) * 2 + 1];
        float xB = il[(mmB * 3 + 2) * 2 + 0] + dl[(mmB * 3 + 2) * 2 + 1];
        float sc = xA + xB;
        #pragma unroll
        for (int off = 1; off < 64; off <<= 1) {
            float vv = __shfl_up(sc, off);
            if (t >= off) sc += vv;
        }
        Smid[mmB] = sc;
        Smid[mmA] = sc - xB;
        if (t == 0) Smid[0] = 0.f;
    }
    __syncthreads();
    if (t < 64) {
        // suffix-LSE over P[mp] = Smid[mp-1] + LSE(ilM+dlM, ilI), mp=1..128.
        int mpA = 128 - 2 * t, mpB = 127 - 2 * t;
        float aM_ = il[(mpA * 3 + 2) * 2 + 0] + dl[(mpA * 3 + 2) * 2 + 0];
        float aI_ = il[(mpA * 3 + 2) * 2 + 1];
        float mA = fmaxf(aM_, aI_);
        float pA = Smid[mpA - 1] + mA + logf(expf(aM_ - mA) + expf(aI_ - mA));
        float bM_ = il[(mpB * 3 + 2) * 2 + 0] + dl[(mpB * 3 + 2) * 2 + 0];
        float bI_ = il[(mpB * 3 + 2) * 2 + 1];
        float mB = fmaxf(bM_, bI_);
        float pB = Smid[mpB - 1] + mB + logf(expf(bM_ - mB) + expf(bI_ - mB));
        float cm = fmaxf(pA, pB);
        float cs = expf(pA - cm) + expf(pB - cm);
        #pragma unroll
        for (int off = 1; off < 64; off <<= 1) {
            float om = __shfl_up(cm, off);
            float os = __shfl_up(cs, off);
            if (t >= off) {
                float M = fmaxf(cm, om);
                cs = cs * expf(cm - M) + os * expf(om - M);
                cm = M;
            }
        }
        Qs[mpB] = cm + logf(cs);
        float em = __shfl_up(cm, 1), es = __shfl_up(cs, 1);
        if (t == 0) Qs[128] = pA;
        else {
            float M = fmaxf(em, pA);
            Qs[mpA] = M + logf(es * expf(em - M) + expf(pA - M));
        }
        if (t == 0) Qs[129] = -1e30f;
    }
    __syncthreads();
    float* uu  = coef + C_UU;
    float* dxM = coef + C_DXM;
    float* dxI = coef + C_DXI;
    float* wM  = coef + C_WM;
    float* wI  = coef + C_WI;
    float* dmd = coef + C_DMID;
    float* pi0 = coef + C_PI0;
    for (int k = t; k < KK; k += 256) {
        if (k == 128) { uu[k] = 0.f; dxM[k] = 0.f; dxI[k] = 0.f; continue; }
        int g  = (k < MP1) ? 0 : 1;
        int n0 = g ? (k - MP1) : (k + 1);
        float i0 = il[(n0 * 3 + g) * 2 + 0], i1 = il[(n0 * 3 + g) * 2 + 1];
        float e0 = dl[(n0 * 3 + g) * 2 + 0], e1 = dl[(n0 * 3 + g) * 2 + 1];
        float diagM = i0 + e0;
        float diagI = i1;
        float src   = i0 + e1;
        float tail  = src - Smid[n0] + Qs[n0 + 1];
        float M3 = fmaxf(fmaxf(diagM, diagI), tail);
        float ssum = expf(diagM - M3) + expf(diagI - M3) + expf(tail - M3);
        float lse = M3 + logf(ssum);
        uu[k]  = expf(src - lse);
        dxM[k] = expf(diagM - lse);
        dxI[k] = expf(diagI - lse);
    }
    for (int mp = t; mp < MP1; mp += 256) {
        wM[mp] = expf(il[(mp * 3 + 2) * 2 + 0] + dl[(mp * 3 + 2) * 2 + 0]);
        wI[mp] = expf(il[(mp * 3 + 2) * 2 + 1]);
    }
    for (int tt = t; tt < 128; tt += 256)
        dmd[tt] = (tt == 0) ? 1.f : expf(il[(tt * 3 + 2) * 2 + 0] + dl[(tt * 3 + 2) * 2 + 1]);
    __syncthreads();
    {   // pi0: O(1) per state via Qs
        float i00 = il[0], i01 = il[1], d00 = dl[0], d01 = dl[1];
        float a00 = i00 + d00, a0129 = i01;
        float tail0 = i00 + d01 + Qs[1];
        float M3 = fmaxf(fmaxf(a00, a0129), tail0);
        float lse0 = M3 + logf(expf(a00 - M3) + expf(a0129 - M3) + expf(tail0 - M3));
        for (int kp = t; kp < KK; kp += 256) {
            int gp = (kp >= MP1);
            int mp = gp ? (kp - MP1) : kp;
            float v;
            if (mp == 0) v = gp ? a0129 : a00;
            else v = i00 + d01 + Smid[mp - 1] +
                     (gp ? il[(mp * 3 + 2) * 2 + 1]
                         : il[(mp * 3 + 2) * 2 + 0] + dl[(mp * 3 + 2) * 2 + 0]);
            pi0[kp] = expf(v - lse0);
        }
    }
}

// ==================== forward scan: 1 wave = TWO batches (dual-chain ILP) ====================
// Two independent recurrences interleaved per step: chain B's instructions
// fill chain A's dependency stalls (solo in-order wave). Coefficients shared.
__global__ __launch_bounds__(64) void k_fwd(const float* __restrict__ ETg,
                                            const float* __restrict__ E2g,
                                            const int* __restrict__ tokg,
                                            const float* __restrict__ coef,
                                            float* __restrict__ out) {
    const float* uu  = coef + C_UU;
    const float* dxM = coef + C_DXM;
    const float* dxI = coef + C_DXI;
    const float* wMg = coef + C_WM;
    const float* wIg = coef + C_WI;
    const float* dmd = coef + C_DMID;
    const float* pi0 = coef + C_PI0;
    __shared__ float ETLA[22 * 256];       // batch A: [tok][lane][4]
    __shared__ float ETLB[22 * 256];       // batch B
    int lane = threadIdx.x;
    int bA = 2 * blockIdx.x, bB = bA + 1;
    {
        const float4* sa = (const float4*)(ETg + (size_t)bA * 5632);
        const float4* sb = (const float4*)(ETg + (size_t)bB * 5632);
        float4* da = (float4*)ETLA;
        float4* db = (float4*)ETLB;
        for (int i = lane; i < 1408; i += 64) { da[i] = sa[i]; db[i] = sb[i]; }
    }
    float e2mA = 0.f, e2iA = 0.f, e2mB = 0.f, e2iB = 0.f;
    if (lane < 22) {
        e2mA = E2g[bA * 44 + lane * 2 + 0];
        e2iA = E2g[bA * 44 + lane * 2 + 1];
        e2mB = E2g[bB * 44 + lane * 2 + 0];
        e2iB = E2g[bB * 44 + lane * 2 + 1];
    }
    int4 tkvA = ((const int4*)(tokg + bA * LL))[lane];
    int4 tkvB = ((const int4*)(tokg + bB * LL))[lane];
    __syncthreads();

    int m0 = 2 * lane, m1 = 2 * lane + 1;
    bool L0 = (lane == 0), L63 = (lane == 63);
    float f63 = L63 ? 1.f : 0.f;
    float cM0 = L0 ? 0.f : uu[m0 - 1];
    float cM1 = uu[m0];
    f32x2 cIp  = {uu[129 + m0], uu[129 + m1]};
    float d0 = dmd[m0], d1v = dmd[m1];
    float Apair = d0 * d1v;
    f32x2 wMp  = {wMg[m0], wMg[m1]};
    f32x2 wIp  = {wIg[m0], wIg[m1]};
    f32x2 xMAp = {L0 ? 0.f : dxM[m0 - 1], dxM[m0]};
    f32x2 xIAp = {L0 ? 0.f : dxI[m0 - 1], dxI[m0]};
    f32x2 xMBp = {dxM[129 + m0], dxM[129 + m1]};
    f32x2 xIBp = {dxI[129 + m0], dxI[129 + m1]};
    f32x2 w2p  = {L63 ? wMg[128] : 0.f, L63 ? wIg[128] : 0.f};
    f32x2 xA2p = {L63 ? dxM[127] : 0.f, L63 ? dxI[127] : 0.f};
    f32x2 xB2p = {L63 ? dxM[257] : 0.f, L63 ? dxI[257] : 0.f};
    f32x2 f63p = {f63, f63};

    // step-invariant Kogge-Stone A-levels (shared by both chains)
    float A0 = Apair;
    float A1 = A0 * updpp<0x111, 0xf, 0xf>(1.f, A0);
    float A2 = A1 * updpp<0x112, 0xf, 0xf>(1.f, A1);
    float A3 = A2 * updpp<0x114, 0xf, 0xf>(1.f, A2);
    float A4 = A3 * updpp<0x118, 0xf, 0xf>(1.f, A3);
    float A5 = A4 * updpp<0x142, 0xa, 0xf>(1.f, A4);
    unsigned long long bbf = __ballot(Apair >= 1.0e-3f);
    int fast = (bbf == 0ULL);

    int lidx = lane * 4;
    // per-chain init: alpha0 = pi0 * E(tok0)
    int tok0A = __builtin_amdgcn_readlane(tkvA.x, 0);
    int tok0B = __builtin_amdgcn_readlane(tkvB.x, 0);
    float4 q0A = *(const float4*)(ETLA + tok0A * 256 + lidx);
    float4 q0B = *(const float4*)(ETLB + tok0B * 256 + lidx);
    f32x2 aMA = {pi0[m0] * q0A.x, pi0[m1] * q0A.y};
    f32x2 aIA = {pi0[129 + m0] * q0A.z, pi0[129 + m1] * q0A.w};
    f32x2 a2A = {f63 * pi0[128] * readlane_f(e2mA, tok0A),
                 f63 * pi0[257] * readlane_f(e2iA, tok0A)};
    f32x2 aMB = {pi0[m0] * q0B.x, pi0[m1] * q0B.y};
    f32x2 aIB = {pi0[129 + m0] * q0B.z, pi0[129 + m1] * q0B.w};
    f32x2 a2B = {f63 * pi0[128] * readlane_f(e2mB, tok0B),
                 f63 * pi0[257] * readlane_f(e2iB, tok0B)};

    int etotA = 0, etotB = 0;
    f32x2 partA = (aMA + aIA) + a2A;
    f32x2 partB = (aMB + aIB) + a2B;

    // 4 rotating E buffers per chain; E2 prefetched alongside (off-chain)
    float4 q1A, q2A, q3A, q4A, q1B, q2B, q3B, q4B;
    float p2m1A, p2i1A, p2m2A, p2i2A, p2m3A, p2i3A, p2m4A, p2i4A;
    float p2m1B, p2i1B, p2m2B, p2i2B, p2m3B, p2i3B, p2m4B, p2i4B;
#define LOADR(SFX, QN, PM, PI, TN)                                           \
    { int tn_ = (TN);                                                        \
      QN = *(const float4*)(ETL##SFX + tn_ * 256 + lidx);                    \
      PM = readlane_f(e2m##SFX, tn_);                                        \
      PI = readlane_f(e2i##SFX, tn_); }
    LOADR(A, q1A, p2m1A, p2i1A, __builtin_amdgcn_readlane(tkvA.y, 0));
    LOADR(B, q1B, p2m1B, p2i1B, __builtin_amdgcn_readlane(tkvB.y, 0));
    LOADR(A, q2A, p2m2A, p2i2A, __builtin_amdgcn_readlane(tkvA.z, 0));
    LOADR(B, q2B, p2m2B, p2i2B, __builtin_amdgcn_readlane(tkvB.z, 0));
    LOADR(A, q3A, p2m3A, p2i3A, __builtin_amdgcn_readlane(tkvA.w, 0));
    LOADR(B, q3B, p2m3B, p2i3B, __builtin_amdgcn_readlane(tkvB.w, 0));
    LOADR(A, q4A, p2m4A, p2i4A, __builtin_amdgcn_readlane(tkvA.x, 1));
    LOADR(B, q4B, p2m4B, p2i4B, __builtin_amdgcn_readlane(tkvB.x, 1));

#define STEP_BODY(SFX, RES, PART, NL, Qr, E2M, E2I)                          \
    {                                                                        \
        f32x2 EMv = {Qr.x, Qr.y};                                            \
        f32x2 EIv = {Qr.z, Qr.w};                                            \
        f32x2 E2v = {E2M, E2I};                                              \
        if (RES) {                                                           \
            float s_ = wave_sum_to63(part##SFX.x + part##SFX.y);             \
            float stot = readlane_f(s_, 63);                                 \
            int sb = __float_as_int(stot) & 0x7f800000;                      \
            etot##SFX += (sb >> 23);                                         \
            float invs = __int_as_float(0x7f000000 - sb);                    \
            f32x2 iv = {invs, invs};                                         \
            EMv *= iv; EIv *= iv; E2v *= iv;                                 \
        }                                                                    \
        float aMp  = updpp<0x138, 0xf, 0xf>(0.f, aM##SFX.y);  /* wf_shr:1 */ \
        float u128 = readlane_f(a2##SFX.x, 63);                              \
        f32x2 aIc = aI##SFX * cIp;                                           \
        float r0 = fmaf(aMp, cM0, aIc.x);                                    \
        float r1 = fmaf(aM##SFX.x, cM1, aIc.y);                              \
        float B = fmaf(d1v, r0, r1);                                         \
        B = fmaf(A0, updpp<0x111, 0xf, 0xf>(0.f, B), B);                     \
        if (NL > 1) {                                                        \
            B = fmaf(A1, updpp<0x112, 0xf, 0xf>(0.f, B), B);                 \
            B = fmaf(A2, updpp<0x114, 0xf, 0xf>(0.f, B), B);                 \
            B = fmaf(A3, updpp<0x118, 0xf, 0xf>(0.f, B), B);                 \
            B = fmaf(A4, updpp<0x142, 0xa, 0xf>(0.f, B), B);                 \
            B = fmaf(A5, updpp<0x143, 0xc, 0xf>(0.f, B), B);                 \
        }                                                                    \
        float G0 = updpp<0x138, 0xf, 0xf>(0.f, B);                           \
        float G1 = fmaf(d0, G0, r0);                                         \
        f32x2 Gp   = {G0, G1};                                               \
        f32x2 aMs  = {aMp, aM##SFX.x};                                       \
        f32x2 u2   = {u128, u128};                                           \
        f32x2 G2p  = {B, B};                                                 \
        f32x2 aM1s = {aM##SFX.y, aM##SFX.y};                                 \
        f32x2 aI2s = {a2##SFX.y, a2##SFX.y};                                 \
        f32x2 mM = wMp * Gp + (xMAp * aMs + (xMBp * aI##SFX + u2));          \
        f32x2 mI = wIp * Gp + (xIAp * aMs + (xIBp * aI##SFX + u2));          \
        f32x2 m2 = w2p * G2p + (xA2p * aM1s + (xB2p * aI2s + u2));           \
        aM##SFX = mM * EMv;                                                  \
        aI##SFX = mI * EIv;                                                  \
        a2##SFX = m2 * E2v * f63p;                                           \
        if (PART) part##SFX = (aM##SFX + aI##SFX) + a2##SFX;                 \
    }

#define RUN_SCAN(NL)                                                         \
    for (int it = 0; it < 63; ++it) {                                        \
        STEP_BODY(A, 1, 0, NL, q1A, p2m1A, p2i1A);                           \
        STEP_BODY(B, 1, 0, NL, q1B, p2m1B, p2i1B);                           \
        LOADR(A, q1A, p2m1A, p2i1A, __builtin_amdgcn_readlane(tkvA.y, it + 1)); \
        LOADR(B, q1B, p2m1B, p2i1B, __builtin_amdgcn_readlane(tkvB.y, it + 1)); \
        STEP_BODY(A, 0, 0, NL, q2A, p2m2A, p2i2A);                           \
        STEP_BODY(B, 0, 0, NL, q2B, p2m2B, p2i2B);                           \
        LOADR(A, q2A, p2m2A, p2i2A, __builtin_amdgcn_readlane(tkvA.z, it + 1)); \
        LOADR(B, q2B, p2m2B, p2i2B, __builtin_amdgcn_readlane(tkvB.z, it + 1)); \
        STEP_BODY(A, 0, 0, NL, q3A, p2m3A, p2i3A);                           \
        STEP_BODY(B, 0, 0, NL, q3B, p2m3B, p2i3B);                           \
        LOADR(A, q3A, p2m3A, p2i3A, __builtin_amdgcn_readlane(tkvA.w, it + 1)); \
        LOADR(B, q3B, p2m3B, p2i3B, __builtin_amdgcn_readlane(tkvB.w, it + 1)); \
        STEP_BODY(A, 0, 1, NL, q4A, p2m4A, p2i4A);                           \
        STEP_BODY(B, 0, 1, NL, q4B, p2m4B, p2i4B);                           \
        int it2 = (it + 2 < 64) ? (it + 2) : 63;                             \
        LOADR(A, q4A, p2m4A, p2i4A, __builtin_amdgcn_readlane(tkvA.x, it2)); \
        LOADR(B, q4B, p2m4B, p2i4B, __builtin_amdgcn_readlane(tkvB.x, it2)); \
    }                                                                        \
    STEP_BODY(A, 1, 0, NL, q1A, p2m1A, p2i1A);                               \
    STEP_BODY(B, 1, 0, NL, q1B, p2m1B, p2i1B);                               \
    STEP_BODY(A, 0, 0, NL, q2A, p2m2A, p2i2A);                               \
    STEP_BODY(B, 0, 0, NL, q2B, p2m2B, p2i2B);                               \
    STEP_BODY(A, 0, 1, NL, q3A, p2m3A, p2i3A);                               \
    STEP_BODY(B, 0, 1, NL, q3B, p2m3B, p2i3B);

    if (fast) { RUN_SCAN(1) }
    else      { RUN_SCAN(6) }
#undef RUN_SCAN
#undef STEP_BODY
#undef LOADR

    float sA = wave_sum_to63(partA.x + partA.y);
    float sB = wave_sum_to63(partB.x + partB.y);
    if (lane == 63) {
        out[bA] = (float)(etotA - 64 * 127) * 0.6931471805599453f + logf(sA);
        out[bB] = (float)(etotB - 64 * 127) * 0.6931471805599453f + logf(sB);
    }
}

extern "C" void kernel_launch(void* const* d_in, const int* in_sizes, int n_in,
                              void* d_out, int out_size, void* d_ws, size_t ws_size,
                              hipStream_t stream) {
    const float* data  = (const float*)d_in[0];
    const float* z     = (const float*)d_in[1];
    const float* dec_W = (const float*)d_in[2];
    const float* dec_b = (const float*)d_in[3];
    const float* ins   = (const float*)d_in[4];
    const float* del   = (const float*)d_in[5];
    const float* invt  = (const float*)d_in[6];
    float* out = (float*)d_out;

    float* ws   = (float*)d_ws;
    float* ETg  = ws + OFF_ETG;
    float* E2g  = ws + OFF_E2G;
    int*   tok  = (int*)(ws + OFF_TOK);
    float* coef = ws + OFF_COEF;

    k_setup<<<1 + EMIS_BLKS + TOK_BLKS, 256, 0, stream>>>(z, dec_W, dec_b, invt,
                                                          data, ins, del, ETg, E2g,
                                                          tok, coef);
    k_fwd<<<BB / 2, 64, 0, stream>>>(ETg, E2g, tok, coef, out);
}

// Round 15
// 65.504 us; speedup vs baseline: 1.0618x; 1.0618x over previous
//
#include <hip/hip_runtime.h>
#include <math.h>

// FactorMuE: profile-HMM forward log-likelihood.
// Dims (static): M=128, Mp1=129, K=258, D=21, ZD=64, B=64, L=256, P=774.
// Reference-fidelity detail: row k=128 of the transition matrix is all
// NEG=-1e32; the reference's float32 row-lse absorbs log(258), so the
// normalized row is 0.0 -> linear outflow weight 1.0 PER DESTINATION.
//
// Structure: k_setup (emis/tok/coef, proven) -> k_gather (pre-gather the
// per-TIME-STEP emission rows so the scan needs no token-dependent
// addressing) -> k_fwd (1 wave/batch, induction-addressed global loads,
// no LDS / readlane / SALU address math in the step loop).
#define MP1 129
#define KK  258
#define DD  21
#define ZDIM 64
#define BB  64
#define LL  256

// ---------------- ws layout (floats; ws = 256MB) ----------------
#define OFF_ETT  0            // ETt[64][256][64][4] = 4194304
#define OFF_E2T  4194304      // E2t[64][256][2]     = 32768
#define OFF_ETG  4227072      // ETg[64][22][64][4]  = 360448
#define OFF_E2G  4587520      // E2g[64][22][2]      = 2816
#define OFF_TOK  4590336      // tok[64][256] int32  = 16384
#define OFF_COEF 4606720      // coef                = 1418
#define C_UU   0
#define C_DXM  258
#define C_DXI  516
#define C_WM   774
#define C_WI   903
#define C_DMID 1032
#define C_PI0  1160

#define EMIS_BLKS 65     // 260 waves >= 258 (c,m)-rows, one wave per row
#define TOK_BLKS  1366   // 5464 waves, 3 rows each, single iteration

typedef float f32x2 __attribute__((ext_vector_type(2)));

// -------- DPP helpers (cross-lane on the VALU pipe) --------
template <int CTRL, int RM, int BM>
__device__ __forceinline__ float updpp(float old, float src) {
    return __int_as_float(__builtin_amdgcn_update_dpp(
        __float_as_int(old), __float_as_int(src), CTRL, RM, BM, false));
}
__device__ __forceinline__ float readlane_f(float v, int lane) {
    return __int_as_float(__builtin_amdgcn_readlane(__float_as_int(v), lane));
}
__device__ __forceinline__ float wave_sum_to63(float s) {
    s += updpp<0x111, 0xf, 0xf>(0.f, s);   // row_shr:1
    s += updpp<0x112, 0xf, 0xf>(0.f, s);   // row_shr:2
    s += updpp<0x114, 0xf, 0xf>(0.f, s);   // row_shr:4
    s += updpp<0x118, 0xf, 0xf>(0.f, s);   // row_shr:8
    s += updpp<0x142, 0xa, 0xf>(0.f, s);   // row_bcast:15
    s += updpp<0x143, 0xc, 0xf>(0.f, s);   // row_bcast:31
    return s;
}

// ==================== fused setup: coef | emis | tok by block role ====================
__global__ __launch_bounds__(256, 1) void k_setup(const float* __restrict__ z,
                                                  const float* __restrict__ W,
                                                  const float* __restrict__ bias,
                                                  const float* __restrict__ invt,
                                                  const float* __restrict__ data,
                                                  const float* __restrict__ ins,
                                                  const float* __restrict__ del,
                                                  float* __restrict__ ETg,
                                                  float* __restrict__ E2g,
                                                  int* __restrict__ tokout,
                                                  float* __restrict__ coef) {
    __shared__ float il[774], dl[774], Smid[129], Qs[130];
    int bid = blockIdx.x;
    int tid = threadIdx.x;

    if (bid >= 1 && bid <= EMIS_BLKS) {
        // ---- emission: wave = one (c,m)-row rr, lane = batch b ----
        int b  = tid & 63;
        int rr = __builtin_amdgcn_readfirstlane((bid - 1) * 4 + (tid >> 6));
        if (rr >= KK) return;
        float it = log1pf(expf(invt[0]));          // softplus
        const float* wb = W + (size_t)rr * DD * ZDIM;   // wave-uniform
        const float* bp = bias + rr * DD;
        float acc[DD];
        #pragma unroll
        for (int d = 0; d < DD; ++d) acc[d] = bp[d];
        const float4* zp = (const float4*)(z + (size_t)b * ZDIM);
        #pragma unroll
        for (int c = 0; c < 4; ++c) {              // 4 chunks x 16 floats (no spill)
            float4 za = zp[4 * c + 0], zb = zp[4 * c + 1];
            float4 zc = zp[4 * c + 2], zd = zp[4 * c + 3];
            #pragma unroll
            for (int d = 0; d < DD; ++d) {
                const float4* wp = (const float4*)(wb + (size_t)d * ZDIM + 16 * c);
                float4 wa = wp[0], wv = wp[1], wc = wp[2], wd = wp[3];
                float a = acc[d];
                a = fmaf(za.x, wa.x, a); a = fmaf(za.y, wa.y, a);
                a = fmaf(za.z, wa.z, a); a = fmaf(za.w, wa.w, a);
                a = fmaf(zb.x, wv.x, a); a = fmaf(zb.y, wv.y, a);
                a = fmaf(zb.z, wv.z, a); a = fmaf(zb.w, wv.w, a);
                a = fmaf(zc.x, wc.x, a); a = fmaf(zc.y, wc.y, a);
                a = fmaf(zc.z, wc.z, a); a = fmaf(zc.w, wc.w, a);
                a = fmaf(zd.x, wd.x, a); a = fmaf(zd.y, wd.y, a);
                a = fmaf(zd.z, wd.z, a); a = fmaf(zd.w, wd.w, a);
                acc[d] = a;
            }
        }
        float mx = acc[0] * it;
        #pragma unroll
        for (int d = 0; d < DD; ++d) { acc[d] *= it; mx = fmaxf(mx, acc[d]); }
        float s = 0.f;
        #pragma unroll
        for (int d = 0; d < DD; ++d) { acc[d] = expf(acc[d] - mx); s += acc[d]; }
        float inv = 1.0f / s;
        // TRANSPOSED write: match m<128 -> ETg[b][d][m>>1][m&1];
        // insert m<128 -> ETg[b][d][m>>1][2+(m&1)]; rows 128/257 -> E2g[b][d][0/1]
        if (rr == 128 || rr == 257) {
            float* eb = E2g + b * 44 + ((rr == 128) ? 0 : 1);
            #pragma unroll
            for (int d = 0; d < DD; ++d) eb[d * 2] = acc[d] * inv;
            eb[DD * 2] = 1.0f;                     // ones row (missing token)
        } else {
            bool ism = rr < 128;
            int m = ism ? rr : rr - MP1;
            int slot = (m >> 1) * 4 + (ism ? 0 : 2) + (m & 1);
            float* eb = ETg + (size_t)b * 5632 + slot;
            #pragma unroll
            for (int d = 0; d < DD; ++d) eb[d * 256] = acc[d] * inv;
            eb[DD * 256] = 1.0f;                   // ones row (missing token)
        }
        return;
    }
    if (bid > EMIS_BLKS) {
        // ---- token extraction via ballot: 3 rows per wave, one iteration ----
        int wid  = (bid - 1 - EMIS_BLKS) * 4 + (tid >> 6);
        int lane = tid & 63;
        int r3   = lane / 21;                            // 0..3 (lane 63 idle)
        int d    = lane - r3 * 21;
        int row  = wid * 3 + r3;
        float v = 0.f;
        if (r3 < 3 && row < BB * LL) v = data[(size_t)row * DD + d];
        unsigned long long m = __ballot(v > 0.5f);
        if (r3 < 3 && d == 0 && row < BB * LL) {
            unsigned long long slice = (m >> (21 * r3)) & 0x1FFFFFULL;
            tokout[row] = slice ? (int)__builtin_ctzll(slice) : DD;
        }
        return;
    }
    // ---- bid 0: transition coefficients (O(1) per row via suffix-LSE) ----
    int t = tid;
    for (int p = t; p < 387; p += 256) {
        float x0 = ins[2 * p], x1 = ins[2 * p + 1];
        float mx = fmaxf(x0, x1);
        float ls = mx + logf(expf(x0 - mx) + expf(x1 - mx));
        il[2 * p] = x0 - ls; il[2 * p + 1] = x1 - ls;
        float y0 = del[2 * p], y1 = del[2 * p + 1];
        float my = fmaxf(y0, y1);
        float lt = my + logf(expf(y0 - my) + expf(y1 - my));
        dl[2 * p] = y0 - lt; dl[2 * p + 1] = y1 - lt;
    }
    __syncthreads();
    if (t < 64) {   // Smid prefix sum, wave 0
        int mmA = 1 + 2 * t, mmB = 2 + 2 * t;
        float xA = il[(mmA * 3 + 2) * 2 + 0] + dl[(mmA * 3 + 2) * 2 + 1];
        float xB = il[(mmB * 3 + 2) * 2 + 0] + dl[(mmB * 3 + 2) * 2 + 1];
        float sc = xA + xB;
        #pragma unroll
        for (int off = 1; off < 64; off <<= 1) {
            float vv = __shfl_up(sc, off);
            if (t >= off) sc += vv;
        }
        Smid[mmB] = sc;
        Smid[mmA] = sc - xB;
        if (t == 0) Smid[0] = 0.f;
    }
    __syncthreads();
    if (t < 64) {
        // suffix-LSE over P[mp] = Smid[mp-1] + LSE(ilM+dlM, ilI), mp=1..128.
        int mpA = 128 - 2 * t, mpB = 127 - 2 * t;
        float aM_ = il[(mpA * 3 + 2) * 2 + 0] + dl[(mpA * 3 + 2) * 2 + 0];
        float aI_ = il[(mpA * 3 + 2) * 2 + 1];
        float mA = fmaxf(aM_, aI_);
        float pA = Smid[mpA - 1] + mA + logf(expf(aM_ - mA) + expf(aI_ - mA));
        float bM_ = il[(mpB * 3 + 2) * 2 + 0] + dl[(mpB * 3 + 2) * 2 + 0];
        float bI_ = il[(mpB * 3 + 2) * 2 + 1];
        float mB = fmaxf(bM_, bI_);
        float pB = Smid[mpB - 1] + mB + logf(expf(bM_ - mB) + expf(bI_ - mB));
        float cm = fmaxf(pA, pB);
        float cs = expf(pA - cm) + expf(pB - cm);
        #pragma unroll
        for (int off = 1; off < 64; off <<= 1) {
            float om = __shfl_up(cm, off);
            float os = __shfl_up(cs, off);
            if (t >= off) {
                float M = fmaxf(cm, om);
                cs = cs * expf(cm - M) + os * expf(om - M);
                cm = M;
            }
        }
        Qs[mpB] = cm + logf(cs);
        float em = __shfl_up(cm, 1), es = __shfl_up(cs, 1);
        if (t == 0) Qs[128] = pA;
        else {
            float M = fmaxf(em, pA);
            Qs[mpA] = M + logf(es * expf(em - M) + expf(pA - M));
        }
        if (t == 0) Qs[129] = -1e30f;
    }
    __syncthreads();
    float* uu  = coef + C_UU;
    float* dxM = coef + C_DXM;
    float* dxI = coef + C_DXI;
    float* wM  = coef + C_WM;
    float* wI  = coef + C_WI;
    float* dmd = coef + C_DMID;
    float* pi0 = coef + C_PI0;
    for (int k = t; k < KK; k += 256) {
        if (k == 128) { uu[k] = 0.f; dxM[k] = 0.f; dxI[k] = 0.f; continue; }
        int g  = (k < MP1) ? 0 : 1;
        int n0 = g ? (k - MP1) : (k + 1);
        float i0 = il[(n0 * 3 + g) * 2 + 0], i1 = il[(n0 * 3 + g) * 2 + 1];
        float e0 = dl[(n0 * 3 + g) * 2 + 0], e1 = dl[(n0 * 3 + g) * 2 + 1];
        float diagM = i0 + e0;
        float diagI = i1;
        float src   = i0 + e1;
        float tail  = src - Smid[n0] + Qs[n0 + 1];
        float M3 = fmaxf(fmaxf(diagM, diagI), tail);
        float ssum = expf(diagM - M3) + expf(diagI - M3) + expf(tail - M3);
        float lse = M3 + logf(ssum);
        uu[k]  = expf(src - lse);
        dxM[k] = expf(diagM - lse);
        dxI[k] = expf(diagI - lse);
    }
    for (int mp = t; mp < MP1; mp += 256) {
        wM[mp] = expf(il[(mp * 3 + 2) * 2 + 0] + dl[(mp * 3 + 2) * 2 + 0]);
        wI[mp] = expf(il[(mp * 3 + 2) * 2 + 1]);
    }
    for (int tt = t; tt < 128; tt += 256)
        dmd[tt] = (tt == 0) ? 1.f : expf(il[(tt * 3 + 2) * 2 + 0] + dl[(tt * 3 + 2) * 2 + 1]);
    __syncthreads();
    {   // pi0: O(1) per state via Qs
        float i00 = il[0], i01 = il[1], d00 = dl[0], d01 = dl[1];
        float a00 = i00 + d00, a0129 = i01;
        float tail0 = i00 + d01 + Qs[1];
        float M3 = fmaxf(fmaxf(a00, a0129), tail0);
        float lse0 = M3 + logf(expf(a00 - M3) + expf(a0129 - M3) + expf(tail0 - M3));
        for (int kp = t; kp < KK; kp += 256) {
            int gp = (kp >= MP1);
            int mp = gp ? (kp - MP1) : kp;
            float v;
            if (mp == 0) v = gp ? a0129 : a00;
            else v = i00 + d01 + Smid[mp - 1] +
                     (gp ? il[(mp * 3 + 2) * 2 + 1]
                         : il[(mp * 3 + 2) * 2 + 0] + dl[(mp * 3 + 2) * 2 + 0]);
            pi0[kp] = expf(v - lse0);
        }
    }
}

// ==================== gather: per-(b,l) emission row -> time-ordered table ====================
__global__ __launch_bounds__(256) void k_gather(const float* __restrict__ ETg,
                                                const float* __restrict__ E2g,
                                                const int* __restrict__ tok,
                                                float* __restrict__ ETt,
                                                float* __restrict__ E2t) {
    int wid  = blockIdx.x * 4 + (threadIdx.x >> 6);   // (b*256 + l), < 16384
    int lane = threadIdx.x & 63;
    int t = __builtin_amdgcn_readfirstlane(tok[wid]);
    int b = wid >> 8;
    float4 v = *(const float4*)(ETg + (size_t)b * 5632 + t * 256 + lane * 4);
    *(float4*)(ETt + (size_t)wid * 256 + lane * 4) = v;
    if (lane == 0) {
        E2t[wid * 2 + 0] = E2g[b * 44 + t * 2 + 0];
        E2t[wid * 2 + 1] = E2g[b * 44 + t * 2 + 1];
    }
}

// ==================== forward scan: 1 wave/batch, induction-addressed loads ====================
// Per step: 2 global loads (E fragment + E2 pair) at pointer+=stride addresses
// prefetched 4 steps ahead; no tokens, readlanes, SALU address math, or LDS.
// Arithmetic identical to round-13. 1-level scan when ballot certifies
// Apair < 1e-3 (dropped terms <= Apair^2 ~1e-6 rel; data has Apair~e^-20).
__global__ __launch_bounds__(64) void k_fwd(const float* __restrict__ ETt,
                                            const float* __restrict__ E2t,
                                            const float* __restrict__ coef,
                                            float* __restrict__ out) {
    const float* uu  = coef + C_UU;
    const float* dxM = coef + C_DXM;
    const float* dxI = coef + C_DXI;
    const float* wMg = coef + C_WM;
    const float* wIg = coef + C_WI;
    const float* dmd = coef + C_DMID;
    const float* pi0 = coef + C_PI0;
    int lane = threadIdx.x;
    int b = blockIdx.x;
    const float* etb = ETt + (size_t)b * LL * 256;
    const float* e2b = E2t + (size_t)b * LL * 2;

    int m0 = 2 * lane, m1 = 2 * lane + 1;
    bool L0 = (lane == 0), L63 = (lane == 63);
    float f63 = L63 ? 1.f : 0.f;
    float cM0 = L0 ? 0.f : uu[m0 - 1];
    float cM1 = uu[m0];
    f32x2 cIp  = {uu[129 + m0], uu[129 + m1]};
    float d0 = dmd[m0], d1v = dmd[m1];
    float Apair = d0 * d1v;
    f32x2 wMp  = {wMg[m0], wMg[m1]};
    f32x2 wIp  = {wIg[m0], wIg[m1]};
    f32x2 xMAp = {L0 ? 0.f : dxM[m0 - 1], dxM[m0]};
    f32x2 xIAp = {L0 ? 0.f : dxI[m0 - 1], dxI[m0]};
    f32x2 xMBp = {dxM[129 + m0], dxM[129 + m1]};
    f32x2 xIBp = {dxI[129 + m0], dxI[129 + m1]};
    f32x2 w2p  = {L63 ? wMg[128] : 0.f, L63 ? wIg[128] : 0.f};
    f32x2 xA2p = {L63 ? dxM[127] : 0.f, L63 ? dxI[127] : 0.f};
    f32x2 xB2p = {L63 ? dxM[257] : 0.f, L63 ? dxI[257] : 0.f};
    f32x2 f63p = {f63, f63};

    // step-invariant Kogge-Stone A-levels
    float A0 = Apair;
    float A1 = A0 * updpp<0x111, 0xf, 0xf>(1.f, A0);
    float A2 = A1 * updpp<0x112, 0xf, 0xf>(1.f, A1);
    float A3 = A2 * updpp<0x114, 0xf, 0xf>(1.f, A2);
    float A4 = A3 * updpp<0x118, 0xf, 0xf>(1.f, A3);
    float A5 = A4 * updpp<0x142, 0xa, 0xf>(1.f, A4);
    unsigned long long bbf = __ballot(Apair >= 1.0e-3f);
    int fast = (bbf == 0ULL);

    // init: alpha0 = pi0 * E(row 0)
    float4 q0 = *((const float4*)etb + lane);
    f32x2 e20 = *(const f32x2*)e2b;
    f32x2 aM = {pi0[m0] * q0.x, pi0[m1] * q0.y};
    f32x2 aI = {pi0[129 + m0] * q0.z, pi0[129 + m1] * q0.w};
    f32x2 a2 = {f63 * pi0[128] * e20.x, f63 * pi0[257] * e20.y};

    int etot = 0;
    f32x2 part = (aM + aI) + a2;

    // rotating buffers, single induction pointers (rows consumed in order)
    const float4* pq = (const float4*)(etb + 256) + lane;   // row 1, this lane
    const f32x2* pe = (const f32x2*)e2b + 1;                // row 1
    float4 q1, q2, q3, q4;
    f32x2 e21, e22, e23, e24;
#define LOADR(QN, EN)                                                        \
    { QN = *pq; pq += 64; EN = *pe; pe += 1; }
    LOADR(q1, e21);   // step 1
    LOADR(q2, e22);   // step 2
    LOADR(q3, e23);   // step 3
    LOADR(q4, e24);   // step 4

#define STEP_BODY(RES, PART, NL, Qr, E2r)                                    \
    {                                                                        \
        f32x2 EMv = {Qr.x, Qr.y};                                            \
        f32x2 EIv = {Qr.z, Qr.w};                                            \
        f32x2 E2v = E2r;                                                     \
        if (RES) {                                                           \
            float s_ = wave_sum_to63(part.x + part.y);                       \
            float stot = readlane_f(s_, 63);                                 \
            int sb = __float_as_int(stot) & 0x7f800000;                      \
            etot += (sb >> 23);                                              \
            float invs = __int_as_float(0x7f000000 - sb);                    \
            f32x2 iv = {invs, invs};                                         \
            EMv *= iv; EIv *= iv; E2v *= iv;                                 \
        }                                                                    \
        float aMp  = updpp<0x138, 0xf, 0xf>(0.f, aM.y);   /* wf_shr:1 */     \
        float u128 = readlane_f(a2.x, 63);                                   \
        f32x2 aIc = aI * cIp;                                                \
        float r0 = fmaf(aMp, cM0, aIc.x);                                    \
        float r1 = fmaf(aM.x, cM1, aIc.y);                                   \
        float B = fmaf(d1v, r0, r1);                                         \
        B = fmaf(A0, updpp<0x111, 0xf, 0xf>(0.f, B), B);                     \
        if (NL > 1) {                                                        \
            B = fmaf(A1, updpp<0x112, 0xf, 0xf>(0.f, B), B);                 \
            B = fmaf(A2, updpp<0x114, 0xf, 0xf>(0.f, B), B);                 \
            B = fmaf(A3, updpp<0x118, 0xf, 0xf>(0.f, B), B);                 \
            B = fmaf(A4, updpp<0x142, 0xa, 0xf>(0.f, B), B);                 \
            B = fmaf(A5, updpp<0x143, 0xc, 0xf>(0.f, B), B);                 \
        }                                                                    \
        float G0 = updpp<0x138, 0xf, 0xf>(0.f, B);                           \
        float G1 = fmaf(d0, G0, r0);                                         \
        f32x2 Gp   = {G0, G1};                                               \
        f32x2 aMs  = {aMp, aM.x};                                            \
        f32x2 u2   = {u128, u128};                                           \
        f32x2 G2p  = {B, B};                                                 \
        f32x2 aM1s = {aM.y, aM.y};                                           \
        f32x2 aI2s = {a2.y, a2.y};                                           \
        f32x2 mM = wMp * Gp + (xMAp * aMs + (xMBp * aI + u2));               \
        f32x2 mI = wIp * Gp + (xIAp * aMs + (xIBp * aI + u2));               \
        f32x2 m2 = w2p * G2p + (xA2p * aM1s + (xB2p * aI2s + u2));           \
        aM = mM * EMv;                                                       \
        aI = mI * EIv;                                                       \
        a2 = m2 * E2v * f63p;                                                \
        if (PART) part = (aM + aI) + a2;                                     \
    }

    // 63 iterations of 4 steps (rescale on first of each 4); final LOADRs
    // read row 256 (guard: lands in the next ws region, value never used).
#define RUN_SCAN(NL)                                                         \
    for (int it = 0; it < 63; ++it) {                                        \
        STEP_BODY(1, 0, NL, q1, e21);                                        \
        LOADR(q1, e21);                                                      \
        STEP_BODY(0, 0, NL, q2, e22);                                        \
        LOADR(q2, e22);                                                      \
        STEP_BODY(0, 0, NL, q3, e23);                                        \
        LOADR(q3, e23);                                                      \
        STEP_BODY(0, 1, NL, q4, e24);                                        \
        LOADR(q4, e24);                                                      \
    }                                                                        \
    STEP_BODY(1, 0, NL, q1, e21);                                            \
    STEP_BODY(0, 0, NL, q2, e22);                                            \
    STEP_BODY(0, 1, NL, q3, e23);

    if (fast) { RUN_SCAN(1) }
    else      { RUN_SCAN(6) }
#undef RUN_SCAN
#undef STEP_BODY
#undef LOADR

    float s = wave_sum_to63(part.x + part.y);
    if (lane == 63)
        out[b] = (float)(etot - 64 * 127) * 0.6931471805599453f + logf(s);
}

extern "C" void kernel_launch(void* const* d_in, const int* in_sizes, int n_in,
                              void* d_out, int out_size, void* d_ws, size_t ws_size,
                              hipStream_t stream) {
    const float* data  = (const float*)d_in[0];
    const float* z     = (const float*)d_in[1];
    const float* dec_W = (const float*)d_in[2];
    const float* dec_b = (const float*)d_in[3];
    const float* ins   = (const float*)d_in[4];
    const float* del   = (const float*)d_in[5];
    const float* invt  = (const float*)d_in[6];
    float* out = (float*)d_out;

    float* ws   = (float*)d_ws;
    float* ETt  = ws + OFF_ETT;
    float* E2t  = ws + OFF_E2T;
    float* ETg  = ws + OFF_ETG;
    float* E2g  = ws + OFF_E2G;
    int*   tok  = (int*)(ws + OFF_TOK);
    float* coef = ws + OFF_COEF;

    k_setup<<<1 + EMIS_BLKS + TOK_BLKS, 256, 0, stream>>>(z, dec_W, dec_b, invt,
                                                          data, ins, del, ETg, E2g,
                                                          tok, coef);
    k_gather<<<BB * LL / 4, 256, 0, stream>>>(ETg, E2g, tok, ETt, E2t);
    k_fwd<<<BB, 64, 0, stream>>>(ETt, E2t, coef, out);
}

// Round 16
// 48.908 us; speedup vs baseline: 1.4221x; 1.3393x over previous
//
#include <hip/hip_runtime.h>
#include <math.h>

// FactorMuE: profile-HMM forward log-likelihood.
// Dims (static): M=128, Mp1=129, K=258, D=21, ZD=64, B=64, L=256, P=774.
// Reference-fidelity detail: row k=128 of the transition matrix is all
// NEG=-1e32; the reference's float32 row-lse absorbs log(258), so the
// normalized row is 0.0 -> linear outflow weight 1.0 PER DESTINATION.
#define MP1 129
#define KK  258
#define DD  21
#define ZDIM 64
#define BB  64
#define LL  256

// ---------------- ws layout (floats) ----------------
// ETg: [64][22][64][4] transposed emission table = 360448
// E2g: [64][22][2]                               = 2816
// tok: [64][256] int32                           = 16384
#define OFF_ETG  0
#define OFF_E2G  360448
#define OFF_TOK  363264
#define OFF_COEF 379648
#define C_UU   0
#define C_DXM  258
#define C_DXI  516
#define C_WM   774
#define C_WI   903
#define C_DMID 1032
#define C_PI0  1160

#define EMIS_BLKS 65     // 260 waves >= 258 (c,m)-rows, one wave per row
#define TOK_BLKS  1366   // 5464 waves, 3 rows each, single iteration

typedef float f32x2 __attribute__((ext_vector_type(2)));

// -------- DPP helpers (cross-lane on the VALU pipe) --------
template <int CTRL, int RM, int BM>
__device__ __forceinline__ float updpp(float old, float src) {
    return __int_as_float(__builtin_amdgcn_update_dpp(
        __float_as_int(old), __float_as_int(src), CTRL, RM, BM, false));
}
__device__ __forceinline__ float readlane_f(float v, int lane) {
    return __int_as_float(__builtin_amdgcn_readlane(__float_as_int(v), lane));
}
__device__ __forceinline__ float wave_sum_to63(float s) {
    s += updpp<0x111, 0xf, 0xf>(0.f, s);   // row_shr:1
    s += updpp<0x112, 0xf, 0xf>(0.f, s);   // row_shr:2
    s += updpp<0x114, 0xf, 0xf>(0.f, s);   // row_shr:4
    s += updpp<0x118, 0xf, 0xf>(0.f, s);   // row_shr:8
    s += updpp<0x142, 0xa, 0xf>(0.f, s);   // row_bcast:15
    s += updpp<0x143, 0xc, 0xf>(0.f, s);   // row_bcast:31
    return s;
}

// ==================== fused setup: coef | emis | tok by block role ====================
__global__ __launch_bounds__(256, 1) void k_setup(const float* __restrict__ z,
                                                  const float* __restrict__ W,
                                                  const float* __restrict__ bias,
                                                  const float* __restrict__ invt,
                                                  const float* __restrict__ data,
                                                  const float* __restrict__ ins,
                                                  const float* __restrict__ del,
                                                  float* __restrict__ ETg,
                                                  float* __restrict__ E2g,
                                                  int* __restrict__ tokout,
                                                  float* __restrict__ coef) {
    __shared__ float il[774], dl[774], Smid[129], Qs[130];
    int bid = blockIdx.x;
    int tid = threadIdx.x;

    if (bid >= 1 && bid <= EMIS_BLKS) {
        // ---- emission: wave = one (c,m)-row rr, lane = batch b ----
        int b  = tid & 63;
        int rr = __builtin_amdgcn_readfirstlane((bid - 1) * 4 + (tid >> 6));
        if (rr >= KK) return;
        float it = log1pf(expf(invt[0]));          // softplus
        const float* wb = W + (size_t)rr * DD * ZDIM;   // wave-uniform
        const float* bp = bias + rr * DD;
        float acc[DD];
        #pragma unroll
        for (int d = 0; d < DD; ++d) acc[d] = bp[d];
        const float4* zp = (const float4*)(z + (size_t)b * ZDIM);
        #pragma unroll
        for (int c = 0; c < 4; ++c) {              // 4 chunks x 16 floats (no spill)
            float4 za = zp[4 * c + 0], zb = zp[4 * c + 1];
            float4 zc = zp[4 * c + 2], zd = zp[4 * c + 3];
            #pragma unroll
            for (int d = 0; d < DD; ++d) {
                const float4* wp = (const float4*)(wb + (size_t)d * ZDIM + 16 * c);
                float4 wa = wp[0], wv = wp[1], wc = wp[2], wd = wp[3];
                float a = acc[d];
                a = fmaf(za.x, wa.x, a); a = fmaf(za.y, wa.y, a);
                a = fmaf(za.z, wa.z, a); a = fmaf(za.w, wa.w, a);
                a = fmaf(zb.x, wv.x, a); a = fmaf(zb.y, wv.y, a);
                a = fmaf(zb.z, wv.z, a); a = fmaf(zb.w, wv.w, a);
                a = fmaf(zc.x, wc.x, a); a = fmaf(zc.y, wc.y, a);
                a = fmaf(zc.z, wc.z, a); a = fmaf(zc.w, wc.w, a);
                a = fmaf(zd.x, wd.x, a); a = fmaf(zd.y, wd.y, a);
                a = fmaf(zd.z, wd.z, a); a = fmaf(zd.w, wd.w, a);
                acc[d] = a;
            }
        }
        float mx = acc[0] * it;
        #pragma unroll
        for (int d = 0; d < DD; ++d) { acc[d] *= it; mx = fmaxf(mx, acc[d]); }
        float s = 0.f;
        #pragma unroll
        for (int d = 0; d < DD; ++d) { acc[d] = expf(acc[d] - mx); s += acc[d]; }
        float inv = 1.0f / s;
        // TRANSPOSED write consumed by k_fwd without repack:
        //   match m<128 : ETg[b][d][m>>1][m&1]
        //   insert m<128: ETg[b][d][m>>1][2+(m&1)]
        //   match 128 / insert 128 -> E2g[b][d][0/1]
        if (rr == 128 || rr == 257) {
            float* eb = E2g + b * 44 + ((rr == 128) ? 0 : 1);
            #pragma unroll
            for (int d = 0; d < DD; ++d) eb[d * 2] = acc[d] * inv;
            eb[DD * 2] = 1.0f;                     // ones row (missing token)
        } else {
            bool ism = rr < 128;
            int m = ism ? rr : rr - MP1;
            int slot = (m >> 1) * 4 + (ism ? 0 : 2) + (m & 1);
            float* eb = ETg + (size_t)b * 5632 + slot;
            #pragma unroll
            for (int d = 0; d < DD; ++d) eb[d * 256] = acc[d] * inv;
            eb[DD * 256] = 1.0f;                   // ones row (missing token)
        }
        return;
    }
    if (bid > EMIS_BLKS) {
        // ---- token extraction via ballot: 3 rows per wave, one iteration ----
        int wid  = (bid - 1 - EMIS_BLKS) * 4 + (tid >> 6);
        int lane = tid & 63;
        int r3   = lane / 21;                            // 0..3 (lane 63 idle)
        int d    = lane - r3 * 21;
        int row  = wid * 3 + r3;
        float v = 0.f;
        if (r3 < 3 && row < BB * LL) v = data[(size_t)row * DD + d];
        unsigned long long m = __ballot(v > 0.5f);
        if (r3 < 3 && d == 0 && row < BB * LL) {
            unsigned long long slice = (m >> (21 * r3)) & 0x1FFFFFULL;
            tokout[row] = slice ? (int)__builtin_ctzll(slice) : DD;
        }
        return;
    }
    // ---- bid 0: transition coefficients (O(1) per row via suffix-LSE) ----
    int t = tid;
    for (int p = t; p < 387; p += 256) {
        float x0 = ins[2 * p], x1 = ins[2 * p + 1];
        float mx = fmaxf(x0, x1);
        float ls = mx + logf(expf(x0 - mx) + expf(x1 - mx));
        il[2 * p] = x0 - ls; il[2 * p + 1] = x1 - ls;
        float y0 = del[2 * p], y1 = del[2 * p + 1];
        float my = fmaxf(y0, y1);
        float lt = my + logf(expf(y0 - my) + expf(y1 - my));
        dl[2 * p] = y0 - lt; dl[2 * p + 1] = y1 - lt;
    }
    __syncthreads();
    if (t < 64) {   // Smid prefix sum, wave 0
        int mmA = 1 + 2 * t, mmB = 2 + 2 * t;
        float xA = il[(mmA * 3 + 2) * 2 + 0] + dl[(mmA * 3 + 2) * 2 + 1];
        float xB = il[(mmB * 3 + 2) * 2 + 0] + dl[(mmB * 3 + 2) * 2 + 1];
        float sc = xA + xB;
        #pragma unroll
        for (int off = 1; off < 64; off <<= 1) {
            float vv = __shfl_up(sc, off);
            if (t >= off) sc += vv;
        }
        Smid[mmB] = sc;
        Smid[mmA] = sc - xB;
        if (t == 0) Smid[0] = 0.f;
    }
    __syncthreads();
    if (t < 64) {
        // suffix-LSE over P[mp] = Smid[mp-1] + LSE(ilM+dlM, ilI), mp=1..128.
        int mpA = 128 - 2 * t, mpB = 127 - 2 * t;
        float aM_ = il[(mpA * 3 + 2) * 2 + 0] + dl[(mpA * 3 + 2) * 2 + 0];
        float aI_ = il[(mpA * 3 + 2) * 2 + 1];
        float mA = fmaxf(aM_, aI_);
        float pA = Smid[mpA - 1] + mA + logf(expf(aM_ - mA) + expf(aI_ - mA));
        float bM_ = il[(mpB * 3 + 2) * 2 + 0] + dl[(mpB * 3 + 2) * 2 + 0];
        float bI_ = il[(mpB * 3 + 2) * 2 + 1];
        float mB = fmaxf(bM_, bI_);
        float pB = Smid[mpB - 1] + mB + logf(expf(bM_ - mB) + expf(bI_ - mB));
        float cm = fmaxf(pA, pB);
        float cs = expf(pA - cm) + expf(pB - cm);
        #pragma unroll
        for (int off = 1; off < 64; off <<= 1) {
            float om = __shfl_up(cm, off);
            float os = __shfl_up(cs, off);
            if (t >= off) {
                float M = fmaxf(cm, om);
                cs = cs * expf(cm - M) + os * expf(om - M);
                cm = M;
            }
        }
        Qs[mpB] = cm + logf(cs);
        float em = __shfl_up(cm, 1), es = __shfl_up(cs, 1);
        if (t == 0) Qs[128] = pA;
        else {
            float M = fmaxf(em, pA);
            Qs[mpA] = M + logf(es * expf(em - M) + expf(pA - M));
        }
        if (t == 0) Qs[129] = -1e30f;
    }
    __syncthreads();
    float* uu  = coef + C_UU;
    float* dxM = coef + C_DXM;
    float* dxI = coef + C_DXI;
    float* wM  = coef + C_WM;
    float* wI  = coef + C_WI;
    float* dmd = coef + C_DMID;
    float* pi0 = coef + C_PI0;
    for (int k = t; k < KK; k += 256) {
        if (k == 128) { uu[k] = 0.f; dxM[k] = 0.f; dxI[k] = 0.f; continue; }
        int g  = (k < MP1) ? 0 : 1;
        int n0 = g ? (k - MP1) : (k + 1);
        float i0 = il[(n0 * 3 + g) * 2 + 0], i1 = il[(n0 * 3 + g) * 2 + 1];
        float e0 = dl[(n0 * 3 + g) * 2 + 0], e1 = dl[(n0 * 3 + g) * 2 + 1];
        float diagM = i0 + e0;
        float diagI = i1;
        float src   = i0 + e1;
        float tail  = src - Smid[n0] + Qs[n0 + 1];
        float M3 = fmaxf(fmaxf(diagM, diagI), tail);
        float ssum = expf(diagM - M3) + expf(diagI - M3) + expf(tail - M3);
        float lse = M3 + logf(ssum);
        uu[k]  = expf(src - lse);
        dxM[k] = expf(diagM - lse);
        dxI[k] = expf(diagI - lse);
    }
    for (int mp = t; mp < MP1; mp += 256) {
        wM[mp] = expf(il[(mp * 3 + 2) * 2 + 0] + dl[(mp * 3 + 2) * 2 + 0]);
        wI[mp] = expf(il[(mp * 3 + 2) * 2 + 1]);
    }
    for (int tt = t; tt < 128; tt += 256)
        dmd[tt] = (tt == 0) ? 1.f : expf(il[(tt * 3 + 2) * 2 + 0] + dl[(tt * 3 + 2) * 2 + 1]);
    __syncthreads();
    {   // pi0: O(1) per state via Qs
        float i00 = il[0], i01 = il[1], d00 = dl[0], d01 = dl[1];
        float a00 = i00 + d00, a0129 = i01;
        float tail0 = i00 + d01 + Qs[1];
        float M3 = fmaxf(fmaxf(a00, a0129), tail0);
        float lse0 = M3 + logf(expf(a00 - M3) + expf(a0129 - M3) + expf(tail0 - M3));
        for (int kp = t; kp < KK; kp += 256) {
            int gp = (kp >= MP1);
            int mp = gp ? (kp - MP1) : kp;
            float v;
            if (mp == 0) v = gp ? a0129 : a00;
            else v = i00 + d01 + Smid[mp - 1] +
                     (gp ? il[(mp * 3 + 2) * 2 + 1]
                         : il[(mp * 3 + 2) * 2 + 0] + dl[(mp * 3 + 2) * 2 + 0]);
            pi0[kp] = expf(v - lse0);
        }
    }
}

// ==================== forward scan: 1 wave/batch (round-13 best: 48.9us) ====================
// Per step: ONE ds_read_b128; E2 pair prefetched via v_readlane at LOADR time
// (4 steps ahead, off the dependent chain); 1-level scan when ballot certifies
// Apair < 1e-3 (dropped terms <= Apair^2 relative ~1e-6 -> <=2.5e-4 nats over
// 255 steps; data has Apair ~ e^-20 so FAST == EXACT below fp32 ulp).
__global__ __launch_bounds__(64) void k_fwd(const float* __restrict__ ETg,
                                            const float* __restrict__ E2g,
                                            const int* __restrict__ tokg,
                                            const float* __restrict__ coef,
                                            float* __restrict__ out) {
    const float* uu  = coef + C_UU;
    const float* dxM = coef + C_DXM;
    const float* dxI = coef + C_DXI;
    const float* wMg = coef + C_WM;
    const float* wIg = coef + C_WI;
    const float* dmd = coef + C_DMID;
    const float* pi0 = coef + C_PI0;
    __shared__ float ETLs[22 * 256];       // [tok][lane][4]
    int lane = threadIdx.x;
    int b = blockIdx.x;
    const float4* srcp = (const float4*)(ETg + (size_t)b * 5632);
    float4* dstp = (float4*)ETLs;
    for (int i = lane; i < 1408; i += 64) dstp[i] = srcp[i];
    float e2m = 0.f, e2i = 0.f;
    if (lane < 22) {
        e2m = E2g[b * 44 + lane * 2 + 0];
        e2i = E2g[b * 44 + lane * 2 + 1];
    }
    int4 tkv = ((const int4*)(tokg + b * LL))[lane];   // tokens 4*lane..4*lane+3
    __syncthreads();

    int m0 = 2 * lane, m1 = 2 * lane + 1;
    bool L0 = (lane == 0), L63 = (lane == 63);
    float f63 = L63 ? 1.f : 0.f;
    float cM0 = L0 ? 0.f : uu[m0 - 1];
    float cM1 = uu[m0];
    f32x2 cIp  = {uu[129 + m0], uu[129 + m1]};
    float d0 = dmd[m0], d1v = dmd[m1];
    float Apair = d0 * d1v;
    f32x2 wMp  = {wMg[m0], wMg[m1]};
    f32x2 wIp  = {wIg[m0], wIg[m1]};
    f32x2 xMAp = {L0 ? 0.f : dxM[m0 - 1], dxM[m0]};
    f32x2 xIAp = {L0 ? 0.f : dxI[m0 - 1], dxI[m0]};
    f32x2 xMBp = {dxM[129 + m0], dxM[129 + m1]};
    f32x2 xIBp = {dxI[129 + m0], dxI[129 + m1]};
    f32x2 w2p  = {L63 ? wMg[128] : 0.f, L63 ? wIg[128] : 0.f};
    f32x2 xA2p = {L63 ? dxM[127] : 0.f, L63 ? dxI[127] : 0.f};
    f32x2 xB2p = {L63 ? dxM[257] : 0.f, L63 ? dxI[257] : 0.f};
    f32x2 f63p = {f63, f63};

    // step-invariant Kogge-Stone A-levels
    float A0 = Apair;
    float A1 = A0 * updpp<0x111, 0xf, 0xf>(1.f, A0);
    float A2 = A1 * updpp<0x112, 0xf, 0xf>(1.f, A1);
    float A3 = A2 * updpp<0x114, 0xf, 0xf>(1.f, A2);
    float A4 = A3 * updpp<0x118, 0xf, 0xf>(1.f, A3);
    float A5 = A4 * updpp<0x142, 0xa, 0xf>(1.f, A4);
    unsigned long long bbf = __ballot(Apair >= 1.0e-3f);
    int fast = (bbf == 0ULL);

    // init: alpha0 = pi0 * E(tok0)
    int lidx = lane * 4;
    int tok0 = __builtin_amdgcn_readlane(tkv.x, 0);
    float4 q0 = *(const float4*)(ETLs + tok0 * 256 + lidx);
    f32x2 e20 = {readlane_f(e2m, tok0), readlane_f(e2i, tok0)};
    f32x2 aM = {pi0[m0] * q0.x, pi0[m1] * q0.y};
    f32x2 aI = {pi0[129 + m0] * q0.z, pi0[129 + m1] * q0.w};
    f32x2 a2 = {f63 * pi0[128] * e20.x, f63 * pi0[257] * e20.y};

    int etot = 0;
    f32x2 part = (aM + aI) + a2;

    // 4 rotating E buffers; E2 pair prefetched alongside (off-chain readlanes)
    float4 q1, q2, q3, q4;
    float p2m1, p2i1, p2m2, p2i2, p2m3, p2i3, p2m4, p2i4;
#define LOADR(QN, PM, PI, TN)                                                \
    { int tn_ = (TN);                                                        \
      QN = *(const float4*)(ETLs + tn_ * 256 + lidx);                        \
      PM = readlane_f(e2m, tn_);                                             \
      PI = readlane_f(e2i, tn_); }
    LOADR(q1, p2m1, p2i1, __builtin_amdgcn_readlane(tkv.y, 0));   // step 1
    LOADR(q2, p2m2, p2i2, __builtin_amdgcn_readlane(tkv.z, 0));   // step 2
    LOADR(q3, p2m3, p2i3, __builtin_amdgcn_readlane(tkv.w, 0));   // step 3
    LOADR(q4, p2m4, p2i4, __builtin_amdgcn_readlane(tkv.x, 1));   // step 4

#define STEP_BODY(RES, PART, NL, Qr, E2M, E2I)                               \
    {                                                                        \
        f32x2 EMv = {Qr.x, Qr.y};                                            \
        f32x2 EIv = {Qr.z, Qr.w};                                            \
        f32x2 E2v = {E2M, E2I};                                              \
        if (RES) {                                                           \
            float s_ = wave_sum_to63(part.x + part.y);                       \
            float stot = readlane_f(s_, 63);                                 \
            int sb = __float_as_int(stot) & 0x7f800000;                      \
            etot += (sb >> 23);                                              \
            float invs = __int_as_float(0x7f000000 - sb);                    \
            f32x2 iv = {invs, invs};                                         \
            EMv *= iv; EIv *= iv; E2v *= iv;                                 \
        }                                                                    \
        float aMp  = updpp<0x138, 0xf, 0xf>(0.f, aM.y);   /* wf_shr:1 */     \
        float u128 = readlane_f(a2.x, 63);                                   \
        f32x2 aIc = aI * cIp;                                                \
        float r0 = fmaf(aMp, cM0, aIc.x);                                    \
        float r1 = fmaf(aM.x, cM1, aIc.y);                                   \
        float B = fmaf(d1v, r0, r1);                                         \
        B = fmaf(A0, updpp<0x111, 0xf, 0xf>(0.f, B), B);                     \
        if (NL > 1) {                                                        \
            B = fmaf(A1, updpp<0x112, 0xf, 0xf>(0.f, B), B);                 \
            B = fmaf(A2, updpp<0x114, 0xf, 0xf>(0.f, B), B);                 \
            B = fmaf(A3, updpp<0x118, 0xf, 0xf>(0.f, B), B);                 \
            B = fmaf(A4, updpp<0x142, 0xa, 0xf>(0.f, B), B);                 \
            B = fmaf(A5, updpp<0x143, 0xc, 0xf>(0.f, B), B);                 \
        }                                                                    \
        float G0 = updpp<0x138, 0xf, 0xf>(0.f, B);                           \
        float G1 = fmaf(d0, G0, r0);                                         \
        f32x2 Gp   = {G0, G1};                                               \
        f32x2 aMs  = {aMp, aM.x};                                            \
        f32x2 u2   = {u128, u128};                                           \
        f32x2 G2p  = {B, B};                                                 \
        f32x2 aM1s = {aM.y, aM.y};                                           \
        f32x2 aI2s = {a2.y, a2.y};                                           \
        f32x2 mM = wMp * Gp + (xMAp * aMs + (xMBp * aI + u2));               \
        f32x2 mI = wIp * Gp + (xIAp * aMs + (xIBp * aI + u2));               \
        f32x2 m2 = w2p * G2p + (xA2p * aM1s + (xB2p * aI2s + u2));           \
        aM = mM * EMv;                                                       \
        aI = mI * EIv;                                                       \
        a2 = m2 * E2v * f63p;                                                \
        if (PART) part = (aM + aI) + a2;                                     \
    }

#define RUN_SCAN(NL)                                                         \
    for (int it = 0; it < 63; ++it) {                                        \
        STEP_BODY(1, 0, NL, q1, p2m1, p2i1);                                 \
        LOADR(q1, p2m1, p2i1, __builtin_amdgcn_readlane(tkv.y, it + 1));     \
        STEP_BODY(0, 0, NL, q2, p2m2, p2i2);                                 \
        LOADR(q2, p2m2, p2i2, __builtin_amdgcn_readlane(tkv.z, it + 1));     \
        STEP_BODY(0, 0, NL, q3, p2m3, p2i3);                                 \
        LOADR(q3, p2m3, p2i3, __builtin_amdgcn_readlane(tkv.w, it + 1));     \
        STEP_BODY(0, 1, NL, q4, p2m4, p2i4);                                 \
        int it2 = (it + 2 < 64) ? (it + 2) : 63;                             \
        LOADR(q4, p2m4, p2i4, __builtin_amdgcn_readlane(tkv.x, it2));        \
    }                                                                        \
    STEP_BODY(1, 0, NL, q1, p2m1, p2i1);                                     \
    STEP_BODY(0, 0, NL, q2, p2m2, p2i2);                                     \
    STEP_BODY(0, 1, NL, q3, p2m3, p2i3);

    if (fast) { RUN_SCAN(1) }
    else      { RUN_SCAN(6) }
#undef RUN_SCAN
#undef STEP_BODY
#undef LOADR

    float s = wave_sum_to63(part.x + part.y);
    if (lane == 63)
        out[b] = (float)(etot - 64 * 127) * 0.6931471805599453f + logf(s);
}

extern "C" void kernel_launch(void* const* d_in, const int* in_sizes, int n_in,
                              void* d_out, int out_size, void* d_ws, size_t ws_size,
                              hipStream_t stream) {
    const float* data  = (const float*)d_in[0];
    const float* z     = (const float*)d_in[1];
    const float* dec_W = (const float*)d_in[2];
    const float* dec_b = (const float*)d_in[3];
    const float* ins   = (const float*)d_in[4];
    const float* del   = (const float*)d_in[5];
    const float* invt  = (const float*)d_in[6];
    float* out = (float*)d_out;

    float* ws   = (float*)d_ws;
    float* ETg  = ws + OFF_ETG;
    float* E2g  = ws + OFF_E2G;
    int*   tok  = (int*)(ws + OFF_TOK);
    float* coef = ws + OFF_COEF;

    k_setup<<<1 + EMIS_BLKS + TOK_BLKS, 256, 0, stream>>>(z, dec_W, dec_b, invt,
                                                          data, ins, del, ETg, E2g,
                                                          tok, coef);
    k_fwd<<<BB, 64, 0, stream>>>(ETg, E2g, tok, coef, out);
}